// Round 6
// baseline (48566.782 us; speedup 1.0000x reference)
//
#include <hip/hip_runtime.h>
#include <cmath>

// ---------------------------------------------------------------------------
// LPCNet-style vocoder on MI355X — round 6: wave0 epilogue + early spin.
// R5 post-mortem: 3.3us/step; 3 barriers, 8-way pl write conflicts (3e8 cyc),
// redundant sample on all waves, gic global loads inside gate phase, exchange
// latency fully exposed after gates.
// R6 (bitwise-identical arithmetic to R5):
//   * wave0 finalizes logits (4/lane) + argmax + sample + gates + h post;
//     waves 1-7 go straight from b1 to the h spin (latency overlap).
//   * 2 barriers/step (was 3); no candv LDS round-trip.
//   * pl XOR-swizzled (og^c8) -> conflict-free writes.
//   * gic row cached in registers, reloaded once per 160 steps.
// ---------------------------------------------------------------------------

#define NB 8
#define NF 64
#define ND 20
#define NH 256
#define NG 768      // 3*NH
#define FS 160
#define NT (NF * FS)   // 10240

#define AGENT __HIP_MEMORY_SCOPE_AGENT
#define HLAY(c) ((((c) >> 4) * 20) + ((c) & 15))   // 16-float groups, 20-float stride

#define AG_W(dst, src) asm volatile("v_accvgpr_write_b32 %0, %1" : "=a"(dst) : "v"(src))
#define AG_R(dst, src) asm volatile("v_accvgpr_read_b32 %0, %1" : "=v"(dst) : "a"(src))
#define VPIN(dst, src) asm volatile("v_mov_b32 %0, %1" : "=v"(dst) : "v"(src))

// ---------------------------------------------------------------------------
// Kernel A: FrameRateNet + gi_cond precompute (unchanged, passing).
// ---------------------------------------------------------------------------
__global__ __launch_bounds__(128) void frn_kernel(
    const float* __restrict__ feat,
    const float* __restrict__ w1,
    const float* __restrict__ b1,
    const float* __restrict__ w2,
    const float* __restrict__ b2,
    const float* __restrict__ fw1,
    const float* __restrict__ fb1,
    const float* __restrict__ fw2,
    const float* __restrict__ fb2,
    const float* __restrict__ wi,
    const float* __restrict__ bi,
    float* __restrict__ gic)
{
    const int bf = blockIdx.x;
    const int b = bf >> 6;
    const int f = bf & 63;
    const int o = threadIdx.x;

    __shared__ float sfeat[5][ND];
    __shared__ float sc1[3][128];
    __shared__ float sc2[128];
    __shared__ float sc3[128];
    __shared__ float scond[128];

    for (int i = o; i < 5 * ND; i += 128) {
        int ff = f - 2 + i / ND;
        int c = i % ND;
        sfeat[i / ND][c] = (ff >= 0 && ff < NF) ? feat[((size_t)b * NF + ff) * ND + c] : 0.f;
    }
    __syncthreads();

    for (int df = 0; df < 3; ++df) {
        int fp = f - 1 + df;
        if (fp >= 0 && fp < NF) {
            float acc = b1[o];
            for (int k = 0; k < 3; ++k)
                for (int c = 0; c < ND; ++c)
                    acc += sfeat[df + k][c] * w1[(k * ND + c) * 128 + o];
            sc1[df][o] = tanhf(acc);
        } else {
            sc1[df][o] = 0.f;
        }
    }
    __syncthreads();

    {
        float acc = b2[o];
        for (int k = 0; k < 3; ++k)
            for (int c = 0; c < 128; ++c)
                acc += sc1[k][c] * w2[(k * 128 + c) * 128 + o];
        sc2[o] = tanhf(acc);
    }
    __syncthreads();
    {
        float acc = fb1[o];
        for (int c = 0; c < 128; ++c) acc += sc2[c] * fw1[c * 128 + o];
        sc3[o] = tanhf(acc);
    }
    __syncthreads();
    {
        float acc = fb2[o];
        for (int c = 0; c < 128; ++c) acc += sc3[c] * fw2[c * 128 + o];
        scond[o] = tanhf(acc);
    }
    __syncthreads();

    for (int r = 0; r < 6; ++r) {
        int j = o + 128 * r;
        float acc = bi[j];
        const float* wr = wi + (size_t)j * 129 + 1;
        for (int c = 0; c < 128; ++c) acc += scond[c] * wr[c];
        gic[(size_t)bf * NG + j] = acc;
    }
}

// ---------------------------------------------------------------------------
// Kernel B: AR loop. 64 blocks (b = bid&7 -> same-XCD heuristic, j = bid>>3),
// 512 threads.
// ---------------------------------------------------------------------------
__global__ __launch_bounds__(512, 2) void ar_kernel(
    const float* __restrict__ gic,    // (8*64, 768)
    const float* __restrict__ wh,     // (768,256) fp32
    const float* __restrict__ ow,     // (256,256) [c][o] native
    const float* __restrict__ wi,     // (768,129) — need column 0
    const float* __restrict__ bh,     // (768,)
    const float* __restrict__ ob,     // (256,)
    float* __restrict__ wav_out,      // (8, 10240)
    float* __restrict__ logits_out,   // (8, 10240, 256)
    unsigned long long* __restrict__ hxp)  // [8][2][256] packed {tag,h}
{
    const int bid = blockIdx.x;
    const int b = bid & 7;            // batch
    const int j = bid >> 3;           // CU index within batch, 0..7
    const int t = threadIdx.x;
    const int qq = t >> 4;            // 0..31: local hidden unit (P1 rows)
    const int ss = t & 15;            // K-chunk of 16 cols (low 4 lane bits)
    const int og = t >> 3;            // 0..63: o-group of 4 (P3)
    const int c8 = t & 7;             // c-chunk of 32 (P3)

    __shared__ __align__(16) float hsp[16 * 20];   // h, skewed groups
    __shared__ __align__(16) float pl[8][256];     // logits partials, XOR-swizzled
    __shared__ float ghfin[32][3];                 // reduced gh rows

    // ---- W_h share -> 48 AGPRs: rows {g, g+256, g+512}, g=32j+qq ----
    float A0[16], A1[16], A2[16];
    {
        const float4* wb = (const float4*)wh;      // row = 64 float4
        size_t r0 = (size_t)(32 * j + qq) * 64 + ss * 4;
        #pragma unroll
        for (int i = 0; i < 4; ++i) {
            float4 x0 = wb[r0 + i];
            AG_W(A0[4*i+0], x0.x); AG_W(A0[4*i+1], x0.y);
            AG_W(A0[4*i+2], x0.z); AG_W(A0[4*i+3], x0.w);
        }
        #pragma unroll
        for (int i = 0; i < 4; ++i) {
            float4 x1 = wb[r0 + 256 * 64 + i];
            AG_W(A1[4*i+0], x1.x); AG_W(A1[4*i+1], x1.y);
            AG_W(A1[4*i+2], x1.z); AG_W(A1[4*i+3], x1.w);
        }
        #pragma unroll
        for (int i = 0; i < 4; ++i) {
            float4 x2 = wb[r0 + 512 * 64 + i];
            AG_W(A2[4*i+0], x2.x); AG_W(A2[4*i+1], x2.y);
            AG_W(A2[4*i+2], x2.z); AG_W(A2[4*i+3], x2.w);
        }
    }
    // ---- FULL out_w -> 128 pinned VGPRs: OW4[i] = ow[c8*32+i][og*4..+3] ----
    float4 OW4[32];
    {
        const float4* op = (const float4*)ow;      // row c = 64 float4
        #pragma unroll
        for (int i = 0; i < 32; ++i) {
            float4 x = op[(size_t)(c8 * 32 + i) * 64 + og];
            VPIN(OW4[i].x, x.x); VPIN(OW4[i].y, x.y);
            VPIN(OW4[i].z, x.z); VPIN(OW4[i].w, x.w);
        }
    }

    // ---- per-thread scalars ----
    float bh_r = 0, bh_z = 0, bh_n = 0, wi_r = 0, wi_z = 0, wi_n = 0;
    if (t < 32) {
        int gr = 32 * j + t;
        bh_r = bh[gr]; bh_z = bh[gr + 256]; bh_n = bh[gr + 512];
        wi_r = wi[(size_t)gr * 129];
        wi_z = wi[(size_t)(gr + 256) * 129];
        wi_n = wi[(size_t)(gr + 512) * 129];
    }
    float ob4[4] = {0.f, 0.f, 0.f, 0.f};
    if (t < 64) {
        #pragma unroll
        for (int m = 0; m < 4; ++m) ob4[m] = ob[64 * m + t];
    }

    if (t < NH) hsp[HLAY(t)] = 0.f;
    float prev = 0.f, yacc = 0.f;
    float g_r = 0.f, g_z = 0.f, g_n = 0.f;   // cached gic row values (t<32)
    int fr = 0, sif = 0;
    __syncthreads();

    const float* gicb = gic + (size_t)b * NF * NG;
    float* lob = logits_out + (size_t)b * NT * NH;
    float* wob = wav_out + (size_t)b * NT;
    unsigned long long* hxb = hxp + (size_t)b * 2 * 256;

    for (int st = 0; st <= NT; ++st) {
        // ---- Phase A: gh_st partials (AGPR) + logits_{st-1} partials (VGPR) ----
        if (st < NT) {
            const float4* h4 = (const float4*)hsp;
            float a0 = 0.f, a1 = 0.f, a2 = 0.f;
            #pragma unroll
            for (int i = 0; i < 4; ++i) {
                float4 hv = h4[ss * 5 + i];
                float w;
                AG_R(w, A0[4*i+0]); a0 += w * hv.x;
                AG_R(w, A0[4*i+1]); a0 += w * hv.y;
                AG_R(w, A0[4*i+2]); a0 += w * hv.z;
                AG_R(w, A0[4*i+3]); a0 += w * hv.w;
                AG_R(w, A1[4*i+0]); a1 += w * hv.x;
                AG_R(w, A1[4*i+1]); a1 += w * hv.y;
                AG_R(w, A1[4*i+2]); a1 += w * hv.z;
                AG_R(w, A1[4*i+3]); a1 += w * hv.w;
                AG_R(w, A2[4*i+0]); a2 += w * hv.x;
                AG_R(w, A2[4*i+1]); a2 += w * hv.y;
                AG_R(w, A2[4*i+2]); a2 += w * hv.z;
                AG_R(w, A2[4*i+3]); a2 += w * hv.w;
            }
            #pragma unroll
            for (int d = 1; d <= 8; d <<= 1) {
                a0 += __shfl_xor(a0, d);
                a1 += __shfl_xor(a1, d);
                a2 += __shfl_xor(a2, d);
            }
            if (ss == 0) {
                ghfin[qq][0] = a0; ghfin[qq][1] = a1; ghfin[qq][2] = a2;
            }
        }
        if (st > 0) {
            const float4* h4 = (const float4*)hsp;
            float4 acc = {0.f, 0.f, 0.f, 0.f};
            #pragma unroll
            for (int i = 0; i < 8; ++i) {
                float4 hv = h4[(c8 * 2 + (i >> 2)) * 5 + (i & 3)];  // wave-uniform
                acc.x += hv.x * OW4[4*i+0].x; acc.y += hv.x * OW4[4*i+0].y;
                acc.z += hv.x * OW4[4*i+0].z; acc.w += hv.x * OW4[4*i+0].w;
                acc.x += hv.y * OW4[4*i+1].x; acc.y += hv.y * OW4[4*i+1].y;
                acc.z += hv.y * OW4[4*i+1].z; acc.w += hv.y * OW4[4*i+1].w;
                acc.x += hv.z * OW4[4*i+2].x; acc.y += hv.z * OW4[4*i+2].y;
                acc.z += hv.z * OW4[4*i+2].z; acc.w += hv.z * OW4[4*i+2].w;
                acc.x += hv.w * OW4[4*i+3].x; acc.y += hv.w * OW4[4*i+3].y;
                acc.z += hv.w * OW4[4*i+3].z; acc.w += hv.w * OW4[4*i+3].w;
            }
            *(float4*)&pl[c8][(og ^ c8) << 2] = acc;   // XOR swizzle: conflict-free
        }
        __syncthreads();   // b1

        // ---- wave0 epilogue: finalize logits + argmax + sample + gates + post ----
        // ---- waves 1-7: jump straight to the h-consume spin (latency overlap) ----
        if (t < 64) {
            if (st > 0) {
                float lg0 = 0.f, lg1 = 0.f, lg2 = 0.f, lg3 = 0.f;
                {
                    // o = 64*m + t ; read with matching swizzle
                    int og0 = t >> 2, q = t & 3;
                    #pragma unroll
                    for (int c = 0; c < 8; ++c) {
                        lg0 += pl[c][(((og0 +  0) ^ c) << 2) | q];
                        lg1 += pl[c][(((og0 + 16) ^ c) << 2) | q];
                        lg2 += pl[c][(((og0 + 32) ^ c) << 2) | q];
                        lg3 += pl[c][(((og0 + 48) ^ c) << 2) | q];
                    }
                    lg0 += ob4[0]; lg1 += ob4[1]; lg2 += ob4[2]; lg3 += ob4[3];
                }
                // store own o-slice [32j, 32j+32)
                {
                    int m0 = j >> 1;
                    if ((t >> 5) == (j & 1)) {
                        float ls = (m0 == 0) ? lg0 : (m0 == 1) ? lg1 : (m0 == 2) ? lg2 : lg3;
                        lob[(size_t)(st - 1) * NH + 64 * m0 + t] = ls;
                    }
                }
                // argmax: local 4 then cross-lane (first-max tie-break)
                float bv = lg0; int bi_ = t;
                if (lg1 > bv) { bv = lg1; bi_ = t + 64; }
                if (lg2 > bv) { bv = lg2; bi_ = t + 128; }
                if (lg3 > bv) { bv = lg3; bi_ = t + 192; }
                #pragma unroll
                for (int d = 32; d > 0; d >>= 1) {
                    float ov = __shfl_down(bv, d);
                    int   oi = __shfl_down(bi_, d);
                    if (ov > bv || (ov == bv && oi < bi_)) { bv = ov; bi_ = oi; }
                }
                int mi = __shfl(bi_, 0);
                float v = ((float)mi + 0.5f) * (1.f / 128.f) - 1.f;
                float av = fabsf(v);
                float mag = (exp2f(8.f * av) - 1.f) * (1.f / 255.f);
                float smp = (v >= 0.f) ? mag : -mag;
                prev = smp;
                yacc = smp + 0.97f * yacc;
                if (j == 0 && t == 0) wob[st - 1] = yacc;
            }
            // gates (t<32) + post packed {tag, h}
            if (st < NT && t < 32) {
                if (sif == 0) {
                    const float* gf = gicb + (size_t)fr * NG;
                    int gu = 32 * j + t;
                    g_r = gf[gu]; g_z = gf[gu + 256]; g_n = gf[gu + 512];
                }
                int gu = 32 * j + t;
                float sr = g_r + wi_r * prev + bh_r + ghfin[t][0];
                float sz = g_z + wi_z * prev + bh_z + ghfin[t][1];
                float ni = g_n + wi_n * prev;
                float nh = bh_n + ghfin[t][2];
                float r = 1.f / (1.f + expf(-sr));
                float z = 1.f / (1.f + expf(-sz));
                float n = tanhf(ni + r * nh);
                int hl = HLAY(gu);
                float hn = (1.f - z) * n + z * hsp[hl];
                hsp[hl] = hn;
                unsigned long long pk =
                    ((unsigned long long)(unsigned)(st + 1) << 32)
                    | (unsigned long long)__float_as_uint(hn);
                __hip_atomic_store(&hxb[(st & 1) * 256 + gu], pk, __ATOMIC_RELAXED, AGENT);
            }
        } else if (st < NT && t < 288) {
            // consumers: fetch the 224 remote h units (already polling when posted)
            unsigned tag = (unsigned)(st + 1);
            int gu = (32 * j + (t - 32)) & 255;
            unsigned long long* sl = &hxb[(st & 1) * 256 + gu];
            unsigned long long pk;
            for (;;) {
                pk = __hip_atomic_load(sl, __ATOMIC_RELAXED, AGENT);
                if ((unsigned)(pk >> 32) == tag) break;
                __builtin_amdgcn_s_sleep(1);
            }
            hsp[HLAY(gu)] = __uint_as_float((unsigned)pk);
        }
        if (st < NT) __syncthreads();   // b3 (uniform)

        if (++sif == FS) { sif = 0; ++fr; }
    }
}

// ---------------------------------------------------------------------------
extern "C" void kernel_launch(void* const* d_in, const int* in_sizes, int n_in,
                              void* d_out, int out_size, void* d_ws, size_t ws_size,
                              hipStream_t stream) {
    (void)in_sizes; (void)n_in; (void)out_size; (void)ws_size;

    const float* feat = (const float*)d_in[0];
    const float* c1w  = (const float*)d_in[1];
    const float* c1b  = (const float*)d_in[2];
    const float* c2w  = (const float*)d_in[3];
    const float* c2b  = (const float*)d_in[4];
    const float* f1w  = (const float*)d_in[5];
    const float* f1b  = (const float*)d_in[6];
    const float* f2w  = (const float*)d_in[7];
    const float* f2b  = (const float*)d_in[8];
    const float* gwi  = (const float*)d_in[9];
    const float* gwh  = (const float*)d_in[10];
    const float* gbi  = (const float*)d_in[11];
    const float* gbh  = (const float*)d_in[12];
    const float* outw = (const float*)d_in[13];
    const float* outb = (const float*)d_in[14];

    // workspace layout
    char* ws = (char*)d_ws;
    float* gic = (float*)ws;                                  // 1,572,864 B
    unsigned long long* hxp = (unsigned long long*)(ws + 1572864);  // 32,768 B
    // tag protocol: 0xAAAAAAAA poison never equals any tag (st+1 <= 10240),
    // so no memset of hxp is required.

    float* wav    = (float*)d_out;                 // (8,10240,1)
    float* logits = (float*)d_out + NB * NT;       // (8,10240,256)

    frn_kernel<<<dim3(NB * NF), dim3(128), 0, stream>>>(
        feat, c1w, c1b, c2w, c2b, f1w, f1b, f2w, f2b, gwi, gbi, gic);
    ar_kernel<<<dim3(64), dim3(512), 0, stream>>>(
        gic, gwh, outw, gwi, gbh, outb, wav, logits, hxp);
}